// Round 1
// baseline (274.086 us; speedup 1.0000x reference)
//
#include <hip/hip_runtime.h>
#include <hip/hip_bf16.h>
#include <cstdint>
#include <cstddef>

typedef float  f32x4  __attribute__((ext_vector_type(4)));
typedef __bf16 bf16x8 __attribute__((ext_vector_type(8)));
typedef __bf16 bf16x4 __attribute__((ext_vector_type(4)));

#define HIDDEN 1024
#define SEQ    2048
#define BATCH  2
#define NQKV   3072
#define MTOT   4096

__device__ __forceinline__ __bf16 f2bf(float f) {
  unsigned u = __builtin_bit_cast(unsigned, f);
  u += 0x7FFFu + ((u >> 16) & 1u);          // round-to-nearest-even
  unsigned short s = (unsigned short)(u >> 16);
  return __builtin_bit_cast(__bf16, s);
}

__device__ __forceinline__ void async16(const void* g, void* l) {
  __builtin_amdgcn_global_load_lds((__attribute__((address_space(1))) void*)(g),
                                   (__attribute__((address_space(3))) void*)(l),
                                   16, 0, 0);
}

// ---------------- fp32 -> bf16 elementwise convert (x) ----------------
__global__ __launch_bounds__(256) void k_convert_x(const float* __restrict__ in,
                                                   __bf16* __restrict__ out) {
  int i = blockIdx.x * 256 + threadIdx.x;
  float4 v = ((const float4*)in)[i];
  bf16x4 o;
  o[0] = f2bf(v.x); o[1] = f2bf(v.y); o[2] = f2bf(v.z); o[3] = f2bf(v.w);
  ((bf16x4*)out)[i] = o;
}

// ---------------- W[K][N] fp32 -> WT[N][K] bf16 ----------------
__global__ __launch_bounds__(256) void k_transpose_w(const float* __restrict__ W,
                                                     __bf16* __restrict__ WT,
                                                     int K, int N) {
  __shared__ float tile[64][65];
  int tx = threadIdx.x & 63, ty = threadIdx.x >> 6;
  int n0 = blockIdx.x * 64, k0 = blockIdx.y * 64;
#pragma unroll
  for (int r = 0; r < 16; r++) {
    int row = r * 4 + ty;
    tile[row][tx] = W[(size_t)(k0 + row) * N + n0 + tx];
  }
  __syncthreads();
#pragma unroll
  for (int r = 0; r < 16; r++) {
    int row = r * 4 + ty;   // n index
    WT[(size_t)(n0 + row) * K + k0 + tx] = f2bf(tile[tx][row]);
  }
}

// ---------------- GEMM: C[M][N] = A[M][K] * BT[N][K]^T + bias ----------------
// m97 structure: 128x128 tile, BK=32, 4 waves of 64x64, global_load_lds(16B).
template <int BF16OUT>
__global__ __launch_bounds__(256) void k_gemm(const __bf16* __restrict__ A,
                                              const __bf16* __restrict__ BT,
                                              const float* __restrict__ bias,
                                              void* __restrict__ Cout,
                                              int M, int N, int K) {
  __shared__ __align__(16) __bf16 As[128 * 32];
  __shared__ __align__(16) __bf16 Bs[128 * 32];
  const int t = threadIdx.x;
  const int lane = t & 63, wv = t >> 6;
  const int ln = lane & 15, quad = lane >> 4;
  const int wm = (wv & 1) * 64, wn = (wv >> 1) * 64;
  const int m0 = blockIdx.y * 128, n0 = blockIdx.x * 128;

  const f32x4 zero4 = {0.f, 0.f, 0.f, 0.f};
  f32x4 acc[4][4];
#pragma unroll
  for (int i = 0; i < 4; i++)
#pragma unroll
    for (int j = 0; j < 4; j++) acc[i][j] = zero4;

  for (int k0 = 0; k0 < K; k0 += 32) {
    __syncthreads();
#pragma unroll
    for (int i = 0; i < 2; i++) {
      int tt = i * 256 + t;
      int row = tt >> 2, ch = tt & 3;
      async16(A  + (size_t)(m0 + row) * K + k0 + ch * 8, As + tt * 8);
      async16(BT + (size_t)(n0 + row) * K + k0 + ch * 8, Bs + tt * 8);
    }
    __syncthreads();
    bf16x8 af[4], bfr[4];
#pragma unroll
    for (int x = 0; x < 4; x++)
      af[x] = *(const bf16x8*)(As + (wm + x * 16 + ln) * 32 + quad * 8);
#pragma unroll
    for (int x = 0; x < 4; x++)
      bfr[x] = *(const bf16x8*)(Bs + (wn + x * 16 + ln) * 32 + quad * 8);
#pragma unroll
    for (int mt = 0; mt < 4; mt++)
#pragma unroll
      for (int nt = 0; nt < 4; nt++)
        acc[mt][nt] = __builtin_amdgcn_mfma_f32_16x16x32_bf16(af[mt], bfr[nt], acc[mt][nt], 0, 0, 0);
  }
#pragma unroll
  for (int nt = 0; nt < 4; nt++) {
    int col = n0 + wn + nt * 16 + ln;
    float bv = bias[col];
#pragma unroll
    for (int mt = 0; mt < 4; mt++) {
#pragma unroll
      for (int r = 0; r < 4; r++) {
        int row = m0 + wm + mt * 16 + quad * 4 + r;
        float v = acc[mt][nt][r] + bv;
        if (BF16OUT) ((__bf16*)Cout)[(size_t)row * N + col] = f2bf(v);
        else         ((float*)Cout)[(size_t)row * N + col] = v;
      }
    }
  }
}

// ---------------- V slice of qkv -> Vt[bh][d=64][s=2048] ----------------
__global__ __launch_bounds__(256) void k_vtrans(const __bf16* __restrict__ qkv,
                                                __bf16* __restrict__ vt) {
  __shared__ __align__(16) __bf16 tile[64 * 80];   // [s][d] padded stride 80
  int t = threadIdx.x;
  int bh = blockIdx.y, b = bh >> 4, h = bh & 15;
  int s0 = blockIdx.x * 64;
  const __bf16* src = qkv + (size_t)(b * SEQ + s0) * NQKV + h * 192 + 128;
#pragma unroll
  for (int i = 0; i < 2; i++) {
    int tt = i * 256 + t; int s = tt >> 3, ch = tt & 7;
    *(bf16x8*)(tile + s * 80 + ch * 8) = *(const bf16x8*)(src + (size_t)s * NQKV + ch * 8);
  }
  __syncthreads();
  __bf16* dst = vt + (size_t)bh * 64 * SEQ + s0;
#pragma unroll
  for (int i = 0; i < 2; i++) {
    int tt = i * 256 + t; int d = tt >> 3, ch = tt & 7;
    bf16x8 o;
#pragma unroll
    for (int j = 0; j < 8; j++) o[j] = tile[(ch * 8 + j) * 80 + d];
    *(bf16x8*)(dst + (size_t)d * SEQ + ch * 8) = o;
  }
}

// ---------------- fused flash attention (bf16 MFMA, fp32 online softmax) ----------------
// grid = 512 blocks: XCD-swizzled so all 16 q-tiles of one (b,h) share an XCD.
__global__ __launch_bounds__(256) void k_attn(const __bf16* __restrict__ qkv,
                                              const __bf16* __restrict__ vt,
                                              __bf16* __restrict__ aout) {
  __shared__ __align__(16) __bf16 smem[32768];   // 64 KB
  __bf16* Qs = smem;            // [128][64]; dead after q-frag loads -> reused as Ps for waves 0,1
  __bf16* Ks = smem + 8192;     // [128][64]
  __bf16* Vs = smem + 16384;    // [64][128]  (V transposed: d major, s minor)

  const int t = threadIdx.x;
  const int lane = t & 63, wv = t >> 6;
  const int ln = lane & 15, quad = lane >> 4;

  int gid = blockIdx.x;
  int slot = gid & 7, j = gid >> 3;
  int bh = slot * 4 + (j >> 4);     // 4 (b,h) pairs per XCD slot
  int qt0 = j & 15;
  const int b = bh >> 4, h = bh & 15;
  const int q0 = qt0 * 128;
  __bf16* Ps = smem + ((wv < 2) ? wv * 4096 : 24576 + (wv - 2) * 4096); // [32][128] per wave

  const __bf16* qbase = qkv + (size_t)b * SEQ * NQKV + h * 192;
  const __bf16* kbase = qbase + 64;
  const __bf16* vbase = vt + (size_t)bh * 64 * SEQ;

#pragma unroll
  for (int i = 0; i < 4; i++) {
    int tt = i * 256 + t; int row = tt >> 3, ch = tt & 7;
    async16(qbase + (size_t)(q0 + row) * NQKV + ch * 8, Qs + tt * 8);
  }
  __syncthreads();
  bf16x8 qf[2][2];
#pragma unroll
  for (int qt = 0; qt < 2; qt++)
#pragma unroll
    for (int dc = 0; dc < 2; dc++)
      qf[qt][dc] = *(const bf16x8*)(Qs + (wv * 32 + qt * 16 + ln) * 64 + dc * 32 + quad * 8);

  const f32x4 zero4 = {0.f, 0.f, 0.f, 0.f};
  f32x4 O[2][4];
  float m_run[2][4], l_run[2][4];
#pragma unroll
  for (int qt = 0; qt < 2; qt++)
#pragma unroll
    for (int r = 0; r < 4; r++) { m_run[qt][r] = -__builtin_inff(); l_run[qt][r] = 0.f; }
#pragma unroll
  for (int qt = 0; qt < 2; qt++)
#pragma unroll
    for (int dt = 0; dt < 4; dt++) O[qt][dt] = zero4;

  const float CE = 0.125f * 1.44269504089f;  // scale * log2(e)

  for (int kt0 = 0; kt0 < SEQ; kt0 += 128) {
    __syncthreads();   // previous tile fully consumed by all waves
#pragma unroll
    for (int i = 0; i < 4; i++) {
      int tt = i * 256 + t; int row = tt >> 3, ch = tt & 7;
      async16(kbase + (size_t)(kt0 + row) * NQKV + ch * 8, Ks + tt * 8);
    }
#pragma unroll
    for (int i = 0; i < 4; i++) {
      int tt = i * 256 + t; int d = tt >> 4, ch = tt & 15;
      async16(vbase + (size_t)d * SEQ + kt0 + ch * 8, Vs + tt * 8);
    }
    __syncthreads();

    // S = Q K^T (raw, scale folded into exp)
    f32x4 Sv[2][8];
#pragma unroll
    for (int kt = 0; kt < 8; kt++) {
      bf16x8 kf0 = *(const bf16x8*)(Ks + (kt * 16 + ln) * 64 + quad * 8);
      bf16x8 kf1 = *(const bf16x8*)(Ks + (kt * 16 + ln) * 64 + 32 + quad * 8);
#pragma unroll
      for (int qt = 0; qt < 2; qt++) {
        f32x4 s = __builtin_amdgcn_mfma_f32_16x16x32_bf16(qf[qt][0], kf0, zero4, 0, 0, 0);
        s = __builtin_amdgcn_mfma_f32_16x16x32_bf16(qf[qt][1], kf1, s, 0, 0, 0);
        Sv[qt][kt] = s;
      }
    }
    // online softmax: rowmax across 8 kt (regs) then 16 lanes (shuffles)
    float alpha[2][4];
#pragma unroll
    for (int qt = 0; qt < 2; qt++)
#pragma unroll
      for (int r = 0; r < 4; r++) {
        float mx = Sv[qt][0][r];
#pragma unroll
        for (int kt = 1; kt < 8; kt++) mx = fmaxf(mx, Sv[qt][kt][r]);
        mx = fmaxf(mx, __shfl_xor(mx, 1));
        mx = fmaxf(mx, __shfl_xor(mx, 2));
        mx = fmaxf(mx, __shfl_xor(mx, 4));
        mx = fmaxf(mx, __shfl_xor(mx, 8));
        float mn = fmaxf(m_run[qt][r], mx);
        alpha[qt][r] = exp2f((m_run[qt][r] - mn) * CE);
        m_run[qt][r] = mn;
      }
    // P = exp2((S - m)*CE); write P to wave-private LDS in A-operand layout
#pragma unroll
    for (int qt = 0; qt < 2; qt++)
#pragma unroll
      for (int r = 0; r < 4; r++) {
        float psum = 0.f;
#pragma unroll
        for (int kt = 0; kt < 8; kt++) {
          float p = exp2f((Sv[qt][kt][r] - m_run[qt][r]) * CE);
          psum += p;
          Ps[(qt * 16 + quad * 4 + r) * 128 + kt * 16 + ln] = f2bf(p);
        }
        l_run[qt][r] = l_run[qt][r] * alpha[qt][r] + psum;
#pragma unroll
        for (int dt = 0; dt < 4; dt++) O[qt][dt][r] *= alpha[qt][r];
      }
    // O += P V   (A = P[q][k] from Ps, B = V[d][k] from Vs, both ds_read_b128)
#pragma unroll
    for (int kc = 0; kc < 4; kc++) {
      bf16x8 pf0 = *(const bf16x8*)(Ps + (ln) * 128 + kc * 32 + quad * 8);
      bf16x8 pf1 = *(const bf16x8*)(Ps + (16 + ln) * 128 + kc * 32 + quad * 8);
#pragma unroll
      for (int dt = 0; dt < 4; dt++) {
        bf16x8 vf = *(const bf16x8*)(Vs + (dt * 16 + ln) * 128 + kc * 32 + quad * 8);
        O[0][dt] = __builtin_amdgcn_mfma_f32_16x16x32_bf16(pf0, vf, O[0][dt], 0, 0, 0);
        O[1][dt] = __builtin_amdgcn_mfma_f32_16x16x32_bf16(pf1, vf, O[1][dt], 0, 0, 0);
      }
    }
  }
  // epilogue: reduce l across 16-lane group, O /= l, stage to LDS, coalesced store
#pragma unroll
  for (int qt = 0; qt < 2; qt++)
#pragma unroll
    for (int r = 0; r < 4; r++) {
      float l = l_run[qt][r];
      l += __shfl_xor(l, 1); l += __shfl_xor(l, 2);
      l += __shfl_xor(l, 4); l += __shfl_xor(l, 8);
      float inv = 1.0f / l;
#pragma unroll
      for (int dt = 0; dt < 4; dt++)
        Ps[(qt * 16 + quad * 4 + r) * 64 + dt * 16 + ln] = f2bf(O[qt][dt][r] * inv);
    }
  __bf16* obase = aout + (size_t)(b * SEQ + q0 + wv * 32) * HIDDEN + h * 64;
#pragma unroll
  for (int i = 0; i < 4; i++) {
    int tt = i * 64 + lane; int row = tt >> 3, ch = tt & 7;
    *(bf16x8*)(obase + (size_t)row * HIDDEN + ch * 8) = *(const bf16x8*)(Ps + row * 64 + ch * 8);
  }
}

extern "C" void kernel_launch(void* const* d_in, const int* in_sizes, int n_in,
                              void* d_out, int out_size, void* d_ws, size_t ws_size,
                              hipStream_t stream) {
  const float* x     = (const float*)d_in[0];
  const float* qkv_w = (const float*)d_in[1];
  const float* qkv_b = (const float*)d_in[2];
  const float* out_w = (const float*)d_in[3];
  const float* out_b = (const float*)d_in[4];

  char* ws = (char*)d_ws;
  __bf16* xb   = (__bf16*)(ws);                       // 4096*1024*2   =  8,388,608
  __bf16* wqkT = (__bf16*)(ws + 8388608);             // 3072*1024*2   =  6,291,456
  __bf16* woT  = (__bf16*)(ws + 14680064);            // 1024*1024*2   =  2,097,152
  __bf16* qkv  = (__bf16*)(ws + 16777216);            // 4096*3072*2   = 25,165,824
  __bf16* vt   = (__bf16*)(ws + 41943040);            // 32*64*2048*2  =  8,388,608
  __bf16* aout = (__bf16*)(ws + 50331648);            // 4096*1024*2   =  8,388,608

  k_convert_x<<<MTOT * HIDDEN / 1024, 256, 0, stream>>>(x, xb);
  k_transpose_w<<<dim3(NQKV / 64, HIDDEN / 64), 256, 0, stream>>>(qkv_w, wqkT, HIDDEN, NQKV);
  k_transpose_w<<<dim3(HIDDEN / 64, HIDDEN / 64), 256, 0, stream>>>(out_w, woT, HIDDEN, HIDDEN);
  k_gemm<1><<<dim3(NQKV / 128, MTOT / 128), 256, 0, stream>>>(xb, wqkT, qkv_b, qkv, MTOT, NQKV, HIDDEN);
  k_vtrans<<<dim3(SEQ / 64, 32), 256, 0, stream>>>(qkv, vt);
  k_attn<<<512, 256, 0, stream>>>(qkv, vt, aout);
  k_gemm<0><<<dim3(HIDDEN / 128, MTOT / 128), 256, 0, stream>>>(aout, woT, out_b, (float*)d_out, MTOT, HIDDEN, HIDDEN);
}